// Round 5
// baseline (296.361 us; speedup 1.0000x reference)
//
#include <hip/hip_runtime.h>
#include <stdint.h>

#define M_DIM 8192
#define N_DIM 4096
#define K_DIM 4096
#define CBN   (K_DIM/8)   // 512 column groups per row
#define ITERS 32          // 64 K-tiles of BK=64, 2 per iteration

typedef __attribute__((ext_vector_type(8))) short bf16x8;
typedef __attribute__((ext_vector_type(8))) unsigned short u16x8;
typedef __attribute__((ext_vector_type(4))) float f32x4;

#define AS_GLOBAL(p) (const __attribute__((address_space(1))) void*)(p)
#define AS_LDS(p)    (__attribute__((address_space(3))) void*)(p)

static __device__ __forceinline__ unsigned short f2bf(float f) {
    union { float f; uint32_t u; } c; c.f = f;
    uint32_t u = c.u;
    return (unsigned short)((u + 0x7fffu + ((u >> 16) & 1u)) >> 16);
}

// ---------------------------------------------------------------------------
// Kernel 1: per (ob, cb) pick top-4 columns (of 8) by L1 mass over 64 rows.
// ---------------------------------------------------------------------------
__global__ __launch_bounds__(256) void venom_sel(const float* __restrict__ W,
                                                 uint16_t* __restrict__ sel) {
    int t   = threadIdx.x;
    int ob  = blockIdx.x;
    int col = blockIdx.y * 256 + t;
    const float* p = W + (size_t)(ob * 64) * K_DIM + col;
    double s = 0.0;
    #pragma unroll 16
    for (int r = 0; r < 64; ++r) s += fabsf(p[(size_t)r * K_DIM]);

    int lane = t & 63;
    int base = lane & ~7;
    double sc[8];
    #pragma unroll
    for (int j = 0; j < 8; ++j) sc[j] = __shfl(s, base + j, 64);

    uint32_t packed = 0;
    #pragma unroll
    for (int c = 0; c < 8; ++c) {
        int rank = 0;
        #pragma unroll
        for (int j = 0; j < 8; ++j)
            rank += (sc[j] > sc[c]) || (sc[j] == sc[c] && j < c);
        if (rank < 4) packed |= (uint32_t)c << (4 * rank);
    }
    if ((lane & 7) == 0) {
        int cb = col >> 3;
        sel[ob * CBN + cb] = (uint16_t)packed;
    }
}

// ---------------------------------------------------------------------------
// Kernel 2: masked bf16 weight pack (top-2 of selected 4 by |w|).
// ---------------------------------------------------------------------------
__global__ __launch_bounds__(256) void venom_pack(const float* __restrict__ W,
                                                  const uint16_t* __restrict__ sel,
                                                  unsigned short* __restrict__ Wb) {
    int gid = blockIdx.x * 256 + threadIdx.x;
    int o  = gid >> 9;
    int cb = gid & (CBN - 1);
    uint32_t pk = sel[(o >> 6) * CBN + cb];
    const float* p = W + (size_t)o * K_DIM + cb * 8;
    float4 a = *(const float4*)p;
    float4 b = *(const float4*)(p + 4);
    float w[8] = {a.x, a.y, a.z, a.w, b.x, b.y, b.z, b.w};

    int   c[4]; float v[4];
    #pragma unroll
    for (int pz = 0; pz < 4; ++pz) {
        c[pz] = (pk >> (4 * pz)) & 7;
        v[pz] = fabsf(w[c[pz]]);
    }
    uint32_t keep = 0;
    #pragma unroll
    for (int pz = 0; pz < 4; ++pz) {
        int cnt = 0;
        #pragma unroll
        for (int q = 0; q < 4; ++q)
            cnt += (v[q] > v[pz]) || (v[q] == v[pz] && q < pz);
        if (cnt < 2) keep |= 1u << c[pz];
    }
    u16x8 out;
    #pragma unroll
    for (int j = 0; j < 8; ++j)
        out[j] = f2bf(((keep >> j) & 1) ? w[j] : 0.0f);
    *(u16x8*)(Wb + (size_t)gid * 8) = out;
}

// ---------------------------------------------------------------------------
// Kernel 3: x f32 -> bf16 (RNE).
// ---------------------------------------------------------------------------
__global__ __launch_bounds__(256) void xcvt(const float* __restrict__ X,
                                            unsigned short* __restrict__ Xb) {
    size_t gid = (size_t)blockIdx.x * 256 + threadIdx.x;
    const float4* p = (const float4*)X + gid * 2;
    float4 a = p[0], b = p[1];
    float w[8] = {a.x, a.y, a.z, a.w, b.x, b.y, b.z, b.w};
    u16x8 out;
    #pragma unroll
    for (int j = 0; j < 8; ++j) out[j] = f2bf(w[j]);
    *(u16x8*)(Xb + gid * 8) = out;
}

// ---------------------------------------------------------------------------
// Kernel 4: 256x256 bf16 GEMM, 8-phase, register double-buffer (phase p issues
// ds_reads for p+1, counted lgkm wait, 16 MFMA on old set, 1 barrier/phase).
// Stages 4 global_load_lds at odd phases; CKPT vmcnt(4) at end of odd phases.
// LAST-ITERATION FIX (round-4 race): when the P5/P7 stages are skipped
// (more==false), CKPT4 at P5 under-waits (only P3's 4 loads outstanding ->
// vmcnt(4) is a no-op -> P6/P7 read buf1.ks1 before P3's stage lands).
// Final iteration now uses vmcnt(0) at P5 and drops P7's checkpoint.
// Steady-state ledger (unchanged, verified):
//   reads@P2top <- staged P7(prev): CKPT@P1 (outst 8 -> drains P7prev)
//   reads@P4top <- staged P1:       CKPT@P3 (outst 8 -> drains P1)
//   reads@P6top <- staged P3:       CKPT@P5 (outst 8 -> drains P3)
//   reads@P8top <- staged P5:       CKPT@P7 (outst 8 -> drains P5)
//   W-after-R: every overwritten region's last ds_read drained >=3 barriers
//   earlier via the counted LGKMs. Never vmcnt(0) in steady state.
// ---------------------------------------------------------------------------
__global__ __launch_bounds__(512, 2) void gemm256(const unsigned short* __restrict__ A,
                                                  const unsigned short* __restrict__ B,
                                                  const float* __restrict__ bias,
                                                  float* __restrict__ C) {
    __shared__ __align__(16) unsigned char smem[131072]; // A:[0,64K) B:[64K,128K)

    int t    = threadIdx.x;
    int wid  = t >> 6;
    int lane = t & 63;
    int l16  = lane & 15;
    int lk   = lane >> 4;
    int wm   = wid >> 2;     // wave row-half (128 rows)
    int wn   = wid & 3;      // wave col-quarter (64 cols)

    // XCD-aware bijective swizzle (512 blocks % 8 == 0)
    int bid = blockIdx.x;
    int swz = (bid & 7) * ((int)gridDim.x >> 3) + (bid >> 3);
    int bm  = swz >> 4;
    int bn  = swz & 15;

    // staging: thread t covers row r=t>>2 (and r+128), phys chunk t&3 holds
    // logical chunk (t&3)^((r>>1)&3) = (t&3)^((t>>3)&3)
    int gch = ((t & 3) ^ ((t >> 3) & 3)) * 8;
    const unsigned short* agbase = A + (size_t)(bm * 256 + (t >> 2)) * K_DIM + gch;
    const unsigned short* bgbase = B + (size_t)(bn * 256 + (t >> 2)) * K_DIM + gch;

    auto stageAB = [&](int tile, int ks, int buf) {
        const unsigned short* ga = agbase + tile * 64 + ks * 32;
        const unsigned short* gb = bgbase + tile * 64 + ks * 32;
        char* la = (char*)smem + buf * 32768 + ks * 16384 + wid * 1024;
        char* lb = la + 65536;
        __builtin_amdgcn_global_load_lds(AS_GLOBAL(ga), AS_LDS(la), 16, 0, 0);
        __builtin_amdgcn_global_load_lds(AS_GLOBAL(ga + (size_t)128 * K_DIM), AS_LDS(la + 8192), 16, 0, 0);
        __builtin_amdgcn_global_load_lds(AS_GLOBAL(gb), AS_LDS(lb), 16, 0, 0);
        __builtin_amdgcn_global_load_lds(AS_GLOBAL(gb + (size_t)128 * K_DIM), AS_LDS(lb + 8192), 16, 0, 0);
    };

    // read-side: row R = base+l16, k-chunk lk -> phys chunk lk^((l16>>1)&3)
    int koff = ((lk ^ ((l16 >> 1) & 3)) << 4);
    const char* ardb = (const char*)smem + (wm * 128 + l16) * 64 + koff;
    const char* brdb = (const char*)smem + 65536 + (wn * 64 + l16) * 64 + koff;

    f32x4 acc[8][4] = {};
    bf16x8 afA[4], afB[4], bfA[4], bfB[4];

#define RD_A(DST, BUF, KS, MH) { _Pragma("unroll")                                   \
    for (int i = 0; i < 4; ++i)                                                      \
        DST[i] = *(const bf16x8*)(ardb + (BUF)*32768 + (KS)*16384 + ((MH)*4+i)*1024); }
#define RD_B(DST, BUF, KS) { _Pragma("unroll")                                       \
    for (int g = 0; g < 4; ++g)                                                      \
        DST[g] = *(const bf16x8*)(brdb + (BUF)*32768 + (KS)*16384 + g*1024); }
#define LGKM(N) { asm volatile("s_waitcnt lgkmcnt(" #N ")" ::: "memory");            \
                  __builtin_amdgcn_sched_barrier(0); }
#define MFMA16(MH, AF, BF) {                                                         \
    __builtin_amdgcn_s_setprio(1);                                                   \
    _Pragma("unroll")                                                                \
    for (int i = 0; i < 4; ++i)                                                      \
        _Pragma("unroll")                                                            \
        for (int g = 0; g < 4; ++g)                                                  \
            acc[(MH)*4+i][g] = __builtin_amdgcn_mfma_f32_16x16x32_bf16(AF[i], BF[g], acc[(MH)*4+i][g], 0, 0, 0); \
    __builtin_amdgcn_s_setprio(0);                                                   \
    __builtin_amdgcn_sched_barrier(0); }
#define CKPT4() { asm volatile("s_waitcnt vmcnt(4)" ::: "memory");                   \
                  __builtin_amdgcn_sched_barrier(0); }
#define CKPT0() { asm volatile("s_waitcnt vmcnt(0)" ::: "memory");                   \
                  __builtin_amdgcn_sched_barrier(0); }
#define BAR()   { __builtin_amdgcn_s_barrier(); __builtin_amdgcn_sched_barrier(0); }

    // prologue: tile0 (buf0) both K-slices; ks0 landed; read set for P1
    stageAB(0, 0, 0);
    stageAB(0, 1, 0);
    CKPT4()
    BAR()
    RD_A(afA, 0, 0, 0) RD_B(bfA, 0, 0)

    for (int it = 0; it < ITERS; ++it) {
        int T1 = 2 * it + 1;
        int T2 = 2 * it + 2;
        bool more = (it < ITERS - 1);

        // P1: MFMA(Mh0, afA,bfA)=T0ks0 | top: afB<-T0ks0Mh1 | stage T1.ks0
        RD_A(afB, 0, 0, 1)
        LGKM(4)
        MFMA16(0, afA, bfA)
        stageAB(T1, 0, 1);
        CKPT4()
        BAR()
        // P2: MFMA(Mh1, afB,bfA) | top: afA<-T0ks1Mh0, bfB<-T0ks1
        RD_A(afA, 0, 1, 0) RD_B(bfB, 0, 1)
        LGKM(8)
        MFMA16(1, afB, bfA)
        BAR()
        // P3: MFMA(Mh0, afA,bfB)=T0ks1 | top: afB<-T0ks1Mh1 | stage T1.ks1
        RD_A(afB, 0, 1, 1)
        LGKM(4)
        MFMA16(0, afA, bfB)
        stageAB(T1, 1, 1);
        CKPT4()
        BAR()
        // P4: MFMA(Mh1, afB,bfB) | top: afA<-T1ks0Mh0, bfA<-T1ks0
        RD_A(afA, 1, 0, 0) RD_B(bfA, 1, 0)
        LGKM(8)
        MFMA16(1, afB, bfB)
        BAR()
        // P5: MFMA(Mh0, afA,bfA)=T1ks0 | top: afB<-T1ks0Mh1 | stage T2.ks0
        RD_A(afB, 1, 0, 1)
        LGKM(4)
        MFMA16(0, afA, bfA)
        if (more) {
            stageAB(T2, 0, 0);
            CKPT4()
        } else {
            CKPT0()   // FIX: drain P3's stage (buf1.ks1) before P6/P7 reads
        }
        BAR()
        // P6: MFMA(Mh1, afB,bfA) | top: afA<-T1ks1Mh0, bfB<-T1ks1
        RD_A(afA, 1, 1, 0) RD_B(bfB, 1, 1)
        LGKM(8)
        MFMA16(1, afB, bfA)
        BAR()
        // P7: MFMA(Mh0, afA,bfB)=T1ks1 | top: afB<-T1ks1Mh1 | stage T2.ks1
        RD_A(afB, 1, 1, 1)
        LGKM(4)
        MFMA16(0, afA, bfB)
        if (more) {
            stageAB(T2, 1, 0);
            CKPT4()
        }
        BAR()
        // P8: MFMA(Mh1, afB,bfB) | top (if more): afA<-T2ks0Mh0, bfA<-T2ks0
        if (more) {
            RD_A(afA, 0, 0, 0) RD_B(bfA, 0, 0)
            LGKM(8)
        } else {
            LGKM(0)
        }
        MFMA16(1, afB, bfB)
        BAR()
    }

    // epilogue: C/D layout col = lane&15, row = (lane>>4)*4 + reg
    int    colb = bn * 256 + wn * 64;
    size_t rowb = (size_t)bm * 256 + wm * 128 + (lk << 2);
    #pragma unroll
    for (int g = 0; g < 4; ++g) {
        int col = colb + g * 16 + l16;
        float bv = bias[col];
        #pragma unroll
        for (int f = 0; f < 8; ++f) {
            size_t r0 = rowb + f * 16;
            #pragma unroll
            for (int rg = 0; rg < 4; ++rg)
                C[(r0 + rg) * N_DIM + col] = acc[f][g][rg] + bv;
        }
    }
}

extern "C" void kernel_launch(void* const* d_in, const int* in_sizes, int n_in,
                              void* d_out, int out_size, void* d_ws, size_t ws_size,
                              hipStream_t stream) {
    const float* x    = (const float*)d_in[0];
    const float* W    = (const float*)d_in[1];
    const float* bias = (const float*)d_in[2];
    float* out = (float*)d_out;

    char* ws = (char*)d_ws;
    unsigned short* xb  = (unsigned short*)ws;                                   // 64 MB
    unsigned short* wb  = (unsigned short*)(ws + (size_t)M_DIM * K_DIM * 2);     // 32 MB
    uint16_t*       sel = (uint16_t*)(ws + (size_t)M_DIM * K_DIM * 2
                                         + (size_t)N_DIM * K_DIM * 2);           // 64 KB

    venom_sel <<<dim3(64, 16), 256, 0, stream>>>(W, sel);
    venom_pack<<<dim3((N_DIM * CBN) / 256), 256, 0, stream>>>(W, sel, wb);
    xcvt      <<<dim3((M_DIM * K_DIM / 8) / 256), 256, 0, stream>>>(x, xb);
    gemm256   <<<dim3((M_DIM / 256) * (N_DIM / 256)), 512, 0, stream>>>(xb, wb, bias, out);
}